// Round 5
// baseline (536.502 us; speedup 1.0000x reference)
//
#include <hip/hip_runtime.h>
#include <hip/hip_bf16.h>
#include <stdint.h>

// ---------------------------------------------------------------------------
// LazyGGUFLinear: y = x @ dequant(scales, codes)^T   (M=N=K=4096)
// R1: 3 kernels, BK=32 GEMM 217us, total 353us.
// R2: BK=64 + XOR swizzle (conflicts 1.68e7 -> 0), GEMM 157.5us = 873 TF.
// R3: cooperative fused kernel -> launch failed. Reverted.
// R4: coalesced prologue -> total unchanged (321us); non-GEMM ~160us is
//     harness-fixed (restore/poison), not our code. GEMM is the only lever.
// R5: AITER-flatmm-style operand streaming: B fragments loaded DIRECT from
//     global to VGPRs (fully coalesced: quads 0-3 of a row = one 64B line),
//     Bs LDS buffer deleted. Halves LDS-pipe traffic (was ~80us/CU, > MFMA's
//     66us) and halves the global_load_lds barrier drain. Natural grid(32,32)
//     so XCD = nt%8 keeps each n-tile's B rows hot in one XCD's L2.
// ---------------------------------------------------------------------------

#define M_DIM 4096
#define N_DIM 4096
#define K_DIM 4096
#define TILE 128
#define BK 64

typedef __attribute__((ext_vector_type(8))) short bf16x8;   // 8 bf16 = 4 VGPRs
typedef __attribute__((ext_vector_type(4))) float f32x4;    // MFMA C/D

__device__ __forceinline__ unsigned short f32_to_bf16_rne(float f) {
    unsigned u = __float_as_uint(f);
    u += 0x7fffu + ((u >> 16) & 1u);   // round-to-nearest-even
    return (unsigned short)(u >> 16);
}

__device__ __forceinline__ void load_lds16(const void* g, void* l) {
    // async global->LDS, 16 B per lane; LDS dest = wave-uniform base + lane*16
    __builtin_amdgcn_global_load_lds(
        (const __attribute__((address_space(1))) unsigned int*)g,
        (__attribute__((address_space(3))) unsigned int*)l, 16, 0, 0);
}

// ---- prologue: fully-coalesced, 4 elements/thread (unchanged from R4) ------
__global__ __launch_bounds__(256) void prologue_kernel(
        const int* __restrict__ codes, const float* __restrict__ scales,
        unsigned short* __restrict__ W,
        const float* __restrict__ x, unsigned short* __restrict__ xb) {
    const int bid = blockIdx.x;
    if (bid < 16384) {
        const int tid = bid * 256 + threadIdx.x;      // 0..4,194,303
        const float s = scales[(tid >> 10) * 128 + ((tid >> 3) & 127)];
        const int4 c = ((const int4*)codes)[tid];     // 16B coalesced
        union { unsigned short u[4]; uint2 v; } p;
        p.u[0] = f32_to_bf16_rne(s * (float)(c.x - 128));
        p.u[1] = f32_to_bf16_rne(s * (float)(c.y - 128));
        p.u[2] = f32_to_bf16_rne(s * (float)(c.z - 128));
        p.u[3] = f32_to_bf16_rne(s * (float)(c.w - 128));
        ((uint2*)W)[tid] = p.v;                       // 8B coalesced
    } else {
        const int tid = (bid - 16384) * 256 + threadIdx.x;
        const float4 f = ((const float4*)x)[tid];     // 16B coalesced
        union { unsigned short u[4]; uint2 v; } p;
        p.u[0] = f32_to_bf16_rne(f.x); p.u[1] = f32_to_bf16_rne(f.y);
        p.u[2] = f32_to_bf16_rne(f.z); p.u[3] = f32_to_bf16_rne(f.w);
        ((uint2*)xb)[tid] = p.v;                      // 8B coalesced
    }
}

// ---- bf16 GEMM: A via LDS (XOR-swizzled, global_load_lds), B streamed ------
// direct global->VGPR. 128x128 tile, BK=64, 4 waves, 64x64/wave.
__global__ __launch_bounds__(256, 4) void gemm_bt_kernel(
        const unsigned short* __restrict__ A,   // [M,K] bf16 (x)
        const unsigned short* __restrict__ B,   // [N,K] bf16 (W)
        float* __restrict__ C) {                // [M,N] fp32
    __shared__ unsigned short As[TILE * BK];    // 16 KB (A only)

    const int wave = threadIdx.x >> 6;
    const int lane = threadIdx.x & 63;

    // natural mapping: x = n-tile -> XCD = nt%8 (B rows per-XCD L2-resident)
    const int m0 = blockIdx.y * TILE;
    const int n0 = blockIdx.x * TILE;

    // A staging: each inst = 64 lanes x 16B = 8 rows x 64k; 4 insts per wave
    // (wave stages 32 rows). Global k-offset XOR-swizzled by row&7 so LDS
    // fragment reads hit all banks evenly (R2-verified: conflicts = 0).
    const int srow  = lane >> 3;                          // 0..7
    const int skofs = ((lane & 7) ^ srow) * 8;            // XOR swizzle
    const int wrow0 = wave * 32;

    const unsigned short* Ag = A + (size_t)(m0 + wrow0 + srow) * K_DIM + skofs;
    unsigned short* AsBase = &As[wrow0 * BK];   // wave-uniform LDS base

    // fragment addressing (A/B-operand layout: row = lane&15, k = quad*8 + j)
    const int frow = lane & 15;
    const int quad = lane >> 4;
    const int wm = (wave >> 1) * 64;        // wave's 64x64 subtile
    const int wn = (wave & 1) * 64;

    // B direct-load base: row = n0+wn+t*16+frow, k = k0 + h*32 + quad*8.
    // Lanes' 16B chunks tile each row's 128B iter-span -> fully coalesced.
    const unsigned short* Bg = B + (size_t)(n0 + wn + frow) * K_DIM + quad * 8;

    f32x4 acc[4][4] = {};

    for (int k0 = 0; k0 < K_DIM; k0 += BK) {
#pragma unroll
        for (int j = 0; j < 4; ++j)
            load_lds16(Ag + k0 + j * 8 * K_DIM, AsBase + j * 8 * BK);

        // B fragments for this iter, straight to VGPRs (8 x 16B, coalesced);
        // their latency drains under the same barrier vmcnt wait as A staging
        bf16x8 b[2][4];
#pragma unroll
        for (int h = 0; h < 2; ++h)
#pragma unroll
            for (int t = 0; t < 4; ++t)
                b[h][t] = *(const bf16x8*)(Bg + (size_t)t * 16 * K_DIM
                                              + k0 + h * 32);
        __syncthreads();    // drains vmcnt (A staging + B frags) + barrier

#pragma unroll
        for (int h = 0; h < 2; ++h) {       // two 16x16x32 K-halves of BK=64
            bf16x8 a[4];
#pragma unroll
            for (int t = 0; t < 4; ++t) {
                const int ch = (h * 4 + quad) ^ (frow & 7);   // un-XOR
                a[t] = *(const bf16x8*)&As[(wm + t * 16 + frow) * BK + ch * 8];
            }
#pragma unroll
            for (int mt = 0; mt < 4; ++mt)
#pragma unroll
                for (int nt = 0; nt < 4; ++nt)
                    acc[mt][nt] = __builtin_amdgcn_mfma_f32_16x16x32_bf16(
                        a[mt], b[h][nt], acc[mt][nt], 0, 0, 0);
        }
        __syncthreads();    // protect As before next staging overwrite
    }

    // epilogue: C/D layout col = lane&15, row = quad*4 + reg  [m89/m91]
#pragma unroll
    for (int mt = 0; mt < 4; ++mt)
#pragma unroll
        for (int nt = 0; nt < 4; ++nt)
#pragma unroll
            for (int r = 0; r < 4; ++r) {
                const int row = m0 + wm + mt * 16 + quad * 4 + r;
                const int col = n0 + wn + nt * 16 + frow;
                C[(size_t)row * N_DIM + col] = acc[mt][nt][r];
            }
}

extern "C" void kernel_launch(void* const* d_in, const int* in_sizes, int n_in,
                              void* d_out, int out_size, void* d_ws, size_t ws_size,
                              hipStream_t stream) {
    const float* x      = (const float*)d_in[0];   // 2*2048*4096 fp32
    const float* scales = (const float*)d_in[1];   // 4096*128 fp32
    const int*   codes  = (const int*)d_in[2];     // 4096*128*32 int32
    float* y = (float*)d_out;                      // 4096*4096 fp32

    unsigned short* Wb = (unsigned short*)d_ws;                       // 32 MB
    unsigned short* xb = (unsigned short*)((char*)d_ws + (size_t)N_DIM * K_DIM * 2); // 32 MB

    prologue_kernel<<<32768, 256, 0, stream>>>(codes, scales, Wb, x, xb);

    dim3 grid(N_DIM / TILE, M_DIM / TILE);  // x = n-tile (XCD key), y = m-tile
    gemm_bt_kernel<<<grid, 256, 0, stream>>>(xb, Wb, y);
}